// Round 7
// baseline (34.928 us; speedup 1.0000x reference)
//
#include <hip/hip_runtime.h>

// ECT: x[N,3] f32, v[3,64] f32, batch[N] int32 (sorted, 64 batches)
// out[64,64,64] f32 = cumsum over bins of per-(batch,bin,dir) histogram.
#define RES 64
#define TD 64
#define NB 64
#define BLK 1024            // 16 waves per block
#define WAVES 16
#define NCOPY 4             // wave-group-private hist copies (contention probe)
#define CHUNK 2048          // points per block (flat grid: N/CHUNK blocks)

// Zero the count accumulator AND precompute batch boundaries (block 0 only).
__global__ __launch_bounds__(256) void ect_init_kernel(
    const int* __restrict__ batch, int N,
    unsigned* __restrict__ counts, int* __restrict__ offs)
{
    int gid = blockIdx.x * 256 + threadIdx.x;     // grid: 1024 blocks
    counts[gid] = 0u;                             // 262144 entries exactly
    if (blockIdx.x == 0 && threadIdx.x <= NB) {
        int val = (int)threadIdx.x;
        int lo = 0, hi = N;
        while (lo < hi) {
            int mid = (lo + hi) >> 1;
            if (batch[mid] < val) lo = mid + 1; else hi = mid;
        }
        offs[threadIdx.x] = lo;                   // offs[64] == N
    }
}

__global__ __launch_bounds__(BLK) void ect_hist_kernel(
    const float* __restrict__ x, const float* __restrict__ v,
    const int* __restrict__ offs, unsigned* __restrict__ counts, int N)
{
    const int start = blockIdx.x * CHUNK;         // flat, perfectly balanced
    const int stop  = min(start + CHUNK, N);
    if (start >= N) return;

    // 4 wave-group-private histograms (64 KB): quarters same-address
    // atomic contention; still 2 blocks/CU (128 KB of 160 KB LDS).
    __shared__ unsigned hist[NCOPY][RES * TD];

    const int t = threadIdx.x & 63;               // lane id = direction
    const int w = threadIdx.x >> 6;               // wave id 0..15
    // per-lane base: copy (w>>2), column t. Atomic addr = hwt + (bin<<6).
    unsigned* __restrict__ hwt = &hist[w >> 2][t];
    const float S = 64.0f / 2.2f;                 // RES / (2*RADIUS)
    const float v0S = v[t] * S;
    const float v1S = v[TD + t] * S;
    const float v2S = v[2 * TD + t] * S;
    // bin = floor(x·v * S + 32), clipped to [0,63]

    // batch of first point: largest b with offs[b] <= start (uniform)
    int lo = 0, hi = NB;
    while (lo < hi) {
        int mid = (lo + hi + 1) >> 1;
        if (offs[mid] <= start) lo = mid; else hi = mid - 1;
    }
    int b = lo;

    // point j's coord k at flat tile offset q=3j+k -> register q>>6, lane q&63
    // (compile-time constants after full unroll -> v_readlane broadcast).
#define SELREG(q, r0, r1, r2) ((q) < 64 ? (r0) : ((q) < 128 ? (r1) : (r2)))
#define RD(q, r0, r1, r2) __uint_as_float(__builtin_amdgcn_readlane(           \
        __float_as_uint(SELREG(q, r0, r1, r2)), (q) & 63))
#define PROC1(j, r0, r1, r2) {                                                 \
        float x0 = RD(3*(j), r0,r1,r2), x1 = RD(3*(j)+1, r0,r1,r2),            \
              x2 = RD(3*(j)+2, r0,r1,r2);                                      \
        float f = fmaf(x0, v0S, fmaf(x1, v1S, fmaf(x2, v2S, 32.0f)));          \
        f = __builtin_amdgcn_fmed3f(f, 0.0f, 63.0f);                           \
        int bin = (int)f;                                                      \
        atomicAdd(hwt + (bin << 6), 1u); }

    int seg = start;
    while (seg < stop) {                          // one iter per batch segment
        while (offs[b + 1] <= seg) ++b;           // skip empty batches (uniform)
        const int segend = min(stop, offs[b + 1]);

        for (int i = threadIdx.x; i < NCOPY * RES * TD; i += BLK)
            hist[0][i] = 0u;
        __syncthreads();

        const int npts = segend - seg;
        const int nf = npts >> 6;                 // full 64-point tiles

        // software-pipelined full tiles: issue next tile's loads, then
        // process current tile from registers (~1300 cyc covers VMEM latency)
        float c0, c1, c2, n0, n1, n2;
        int tl = w;
        if (tl < nf) {
            const int fb = 3 * (seg + (tl << 6)) + t;
            c0 = x[fb]; c1 = x[fb + 64]; c2 = x[fb + 128];
        }
        for (; tl < nf; tl += WAVES) {
            const int tn = tl + WAVES;
            if (tn < nf) {                        // prefetch next tile (uniform)
                const int fb = 3 * (seg + (tn << 6)) + t;
                n0 = x[fb]; n1 = x[fb + 64]; n2 = x[fb + 128];
            }
            #pragma unroll
            for (int j = 0; j < 64; ++j) PROC1(j, c0, c1, c2);
            if (tn < nf) { c0 = n0; c1 = n1; c2 = n2; }
        }

        // ragged segment-tail tile (at most one), owned by wave (nf mod 16)
        const int rem = npts & 63;
        if (rem && w == (nf & (WAVES - 1))) {
            const int fb = 3 * (seg + (nf << 6)) + t;
            const int lim = 3 * segend;
            float l0 = (fb       < lim) ? x[fb]       : 0.0f;
            float l1 = (fb +  64 < lim) ? x[fb +  64] : 0.0f;
            float l2 = (fb + 128 < lim) ? x[fb + 128] : 0.0f;
            #pragma unroll
            for (int j = 0; j < 64; ++j) {
                if (j < rem) PROC1(j, l0, l1, l2);   // wave-uniform guard
            }
        }
        __syncthreads();

        // flush all copies into batch b's slab (exact uint atomics)
        unsigned* __restrict__ gb = counts + b * (RES * TD);
        for (int i = threadIdx.x; i < RES * TD; i += BLK) {
            unsigned h = hist[0][i] + hist[1][i] + hist[2][i] + hist[3][i];
            if (h) atomicAdd(&gb[i], h);
        }
        if (segend < stop) __syncthreads();       // before re-zeroing hist
        seg = segend;
    }
#undef PROC1
#undef RD
#undef SELREG
}

// In-place: d_out holds uint counts [64][64][64]; convert to cumulative f32
// over the bin axis. One block per batch b, lane t owns column (b,t).
__global__ __launch_bounds__(64) void ect_cumsum_kernel(unsigned* __restrict__ u)
{
    int b = blockIdx.x, t = threadIdx.x;
    int base = b * (RES * TD) + t;

    unsigned vals[RES];
    #pragma unroll
    for (int r = 0; r < RES; ++r) vals[r] = u[base + (r << 6)];

    unsigned acc = 0u;
    #pragma unroll
    for (int r = 0; r < RES; ++r) {
        acc += vals[r];
        u[base + (r << 6)] = __float_as_uint((float)acc);  // counts < 2^24: exact
    }
}

extern "C" void kernel_launch(void* const* d_in, const int* in_sizes, int n_in,
                              void* d_out, int out_size, void* d_ws, size_t ws_size,
                              hipStream_t stream) {
    const float* x = (const float*)d_in[0];          // [N,3]
    const float* v = (const float*)d_in[1];          // [3,64]
    const int* batch = (const int*)d_in[2];          // [N] int32, sorted
    const int N = in_sizes[2];
    int* offs = (int*)d_ws;                          // 65 ints of scratch

    ect_init_kernel<<<(NB * RES * TD) / 256, 256, 0, stream>>>(
        batch, N, (unsigned*)d_out, offs);

    const int nblocks = (N + CHUNK - 1) / CHUNK;     // 512 for N=1M
    ect_hist_kernel<<<nblocks, BLK, 0, stream>>>(x, v, offs, (unsigned*)d_out, N);

    ect_cumsum_kernel<<<NB, 64, 0, stream>>>((unsigned*)d_out);
}

// Round 8
// 32.737 us; speedup vs baseline: 1.0669x; 1.0669x over previous
//
#include <hip/hip_runtime.h>

// ECT: x[N,3] f32, v[3,64] f32, batch[N] int32 (sorted, 64 batches)
// out[64,64,64] f32 = cumsum over bins of per-(batch,bin,dir) histogram.
// Structure: init (zero out + batch offsets) -> hist (LDS histogram,
// fused local-cumsum flush via exact f32 atomics). Cumsum kernel eliminated:
// sum over blocks of cumsum(local hist) == cumsum(global hist) by linearity.
#define RES 64
#define TD 64
#define NB 64
#define BLK 1024            // 16 waves per block
#define WAVES 16
#define CHUNK 2048          // points per block (flat grid: N/CHUNK blocks)

// Zero the f32 accumulator AND precompute batch boundaries (block 0 only).
__global__ __launch_bounds__(256) void ect_init_kernel(
    const int* __restrict__ batch, int N,
    float4* __restrict__ out4, int* __restrict__ offs)
{
    int gid = blockIdx.x * 256 + threadIdx.x;     // grid: 256 blocks
    out4[gid] = float4{0.f, 0.f, 0.f, 0.f};       // 65536 float4 = 1 MB exactly
    if (blockIdx.x == 0 && threadIdx.x <= NB) {
        int val = (int)threadIdx.x;
        int lo = 0, hi = N;
        while (lo < hi) {
            int mid = (lo + hi) >> 1;
            if (batch[mid] < val) lo = mid + 1; else hi = mid;
        }
        offs[threadIdx.x] = lo;                   // offs[64] == N
    }
}

__global__ __launch_bounds__(BLK) void ect_hist_kernel(
    const float* __restrict__ x, const float* __restrict__ v,
    const int* __restrict__ offs, float* __restrict__ out, int N)
{
    const int start = blockIdx.x * CHUNK;         // flat, perfectly balanced
    const int stop  = min(start + CHUNK, N);
    if (start >= N) return;

    __shared__ unsigned hist[2][RES * TD];        // 32 KB, 2 blocks/CU
    __shared__ unsigned col_part[TD][17];         // prefix scratch (+1 pad)

    const int t = threadIdx.x & 63;               // lane id = direction
    const int w = threadIdx.x >> 6;               // wave id 0..15
    unsigned* __restrict__ hwt = &hist[w >> 3][t];// waves 0-7 -> A, 8-15 -> B
    const float S = 64.0f / 2.2f;                 // RES / (2*RADIUS)
    const float v0S = v[t] * S;
    const float v1S = v[TD + t] * S;
    const float v2S = v[2 * TD + t] * S;
    // bin = floor(x·v * S + 32), clipped to [0,63]

    // batch of first point: largest b with offs[b] <= start (uniform)
    int lo = 0, hi = NB;
    while (lo < hi) {
        int mid = (lo + hi + 1) >> 1;
        if (offs[mid] <= start) lo = mid; else hi = mid - 1;
    }
    int b = lo;

    // point j's coord k at flat tile offset q=3j+k -> register q>>6, lane q&63
    // (compile-time constants after full unroll -> v_readlane broadcast).
#define SELREG(q, r0, r1, r2) ((q) < 64 ? (r0) : ((q) < 128 ? (r1) : (r2)))
#define RD(q, r0, r1, r2) __uint_as_float(__builtin_amdgcn_readlane(           \
        __float_as_uint(SELREG(q, r0, r1, r2)), (q) & 63))
#define PROC1(j, r0, r1, r2) {                                                 \
        float x0 = RD(3*(j), r0,r1,r2), x1 = RD(3*(j)+1, r0,r1,r2),            \
              x2 = RD(3*(j)+2, r0,r1,r2);                                      \
        float f = fmaf(x0, v0S, fmaf(x1, v1S, fmaf(x2, v2S, 32.0f)));          \
        f = __builtin_amdgcn_fmed3f(f, 0.0f, 63.0f);                           \
        int bin = (int)f;                                                      \
        atomicAdd(hwt + (bin << 6), 1u); }

    int seg = start;
    while (seg < stop) {                          // one iter per batch segment
        while (offs[b + 1] <= seg) ++b;           // skip empty batches (uniform)
        const int segend = min(stop, offs[b + 1]);

        for (int i = threadIdx.x; i < 2 * RES * TD; i += BLK) hist[0][i] = 0u;
        __syncthreads();

        const int npts = segend - seg;
        const int nf = npts >> 6;                 // full 64-point tiles

        // software-pipelined full tiles: issue next tile's loads, then
        // process current tile from registers (~1300 cyc covers VMEM latency)
        float c0, c1, c2, n0, n1, n2;
        int tl = w;
        if (tl < nf) {
            const int fb = 3 * (seg + (tl << 6)) + t;
            c0 = x[fb]; c1 = x[fb + 64]; c2 = x[fb + 128];
        }
        for (; tl < nf; tl += WAVES) {
            const int tn = tl + WAVES;
            if (tn < nf) {                        // prefetch next tile (uniform)
                const int fb = 3 * (seg + (tn << 6)) + t;
                n0 = x[fb]; n1 = x[fb + 64]; n2 = x[fb + 128];
            }
            #pragma unroll
            for (int j = 0; j < 64; ++j) PROC1(j, c0, c1, c2);
            if (tn < nf) { c0 = n0; c1 = n1; c2 = n2; }
        }

        // ragged segment-tail tile (at most one), owned by wave (nf mod 16)
        const int rem = npts & 63;
        if (rem && w == (nf & (WAVES - 1))) {
            const int fb = 3 * (seg + (nf << 6)) + t;
            const int lim = 3 * segend;
            float l0 = (fb       < lim) ? x[fb]       : 0.0f;
            float l1 = (fb +  64 < lim) ? x[fb +  64] : 0.0f;
            float l2 = (fb + 128 < lim) ? x[fb + 128] : 0.0f;
            #pragma unroll
            for (int j = 0; j < 64; ++j) {
                if (j < rem) PROC1(j, l0, l1, l2);   // wave-uniform guard
            }
        }
        __syncthreads();

        // Fused flush: local cumsum over bins, then exact f32 atomics.
        // Wave w's lane t handles column t, bins [4w, 4w+4).
        unsigned vals[4];
        {
            unsigned s = 0;
            #pragma unroll
            for (int i = 0; i < 4; ++i) {
                int r = (w << 2) + i;
                s += hist[0][(r << 6) + t] + hist[1][(r << 6) + t];
                vals[i] = s;                      // inclusive prefix of my 4
            }
            col_part[t][w] = s;                   // my column-segment total
        }
        __syncthreads();
        {
            unsigned off = 0;
            for (int j = 0; j < w; ++j) off += col_part[t][j];  // uniform trip
            float* __restrict__ gb = out + b * (RES * TD) + t;
            #pragma unroll
            for (int i = 0; i < 4; ++i) {
                int r = (w << 2) + i;
                atomicAdd(gb + (r << 6), (float)(vals[i] + off)); // coalesced
            }
        }
        if (segend < stop) __syncthreads();       // before re-zeroing hist
        seg = segend;
    }
#undef PROC1
#undef RD
#undef SELREG
}

extern "C" void kernel_launch(void* const* d_in, const int* in_sizes, int n_in,
                              void* d_out, int out_size, void* d_ws, size_t ws_size,
                              hipStream_t stream) {
    const float* x = (const float*)d_in[0];          // [N,3]
    const float* v = (const float*)d_in[1];          // [3,64]
    const int* batch = (const int*)d_in[2];          // [N] int32, sorted
    const int N = in_sizes[2];
    int* offs = (int*)d_ws;                          // 65 ints of scratch

    ect_init_kernel<<<(NB * RES * TD) / (256 * 4), 256, 0, stream>>>(
        batch, N, (float4*)d_out, offs);

    const int nblocks = (N + CHUNK - 1) / CHUNK;     // 512 for N=1M
    ect_hist_kernel<<<nblocks, BLK, 0, stream>>>(x, v, offs, (float*)d_out, N);
}